// Round 2
// baseline (558.781 us; speedup 1.0000x reference)
//
#include <hip/hip_runtime.h>
#include <math.h>

// B=16, N=2048, F=64, T=32; x:(B,N,F,T) fp32 256MiB; out:(B,T,T) fp32.
// Factorization:
//   lhs1[b,t,f] = sum_n x[b,n,f,t]*U1[n]
//   rhs[b,n,t]  = sum_f U3[f]*x[b,n,f,t]
//   R2[b,f,s]   = sum_n U2[f,n]*rhs[b,n,s]
//   product[b,t,s] = sum_f lhs1[b,t,f]*R2[b,f,s]
//   E = V_e @ sigmoid(product + b_e);  softmax over axis 1 (u).
// AI ~ 1.6 FLOP/B -> memory-bound; floor = 268MB/6.3TB/s ~= 43us (k1).

#define BDIM 16
#define NDIM 2048
#define FDIM 64
#define TDIM 32
#define GPB  64   // blocks per batch in k1 (1024 blocks total, 4/CU, 16 waves/CU)

// ---------------- kernel 1: single pass over x ----------------
// grid = BDIM*GPB blocks, 256 threads (4 waves). Each wave handles
// n = (gb*4+wave) + k*(GPB*4). Per n: 8 float4 loads/lane covering the
// 64x32 slice (each load: 64 lanes x 16B = 1KB contiguous); accumulate
// lhs1 partial in regs, rhs via shfl_xor reduce over lane bits 3..5.
__global__ __launch_bounds__(256) void k1_pass(
    const float* __restrict__ x, const float* __restrict__ U1,
    const float* __restrict__ U3, float* __restrict__ rhs_ws,
    float* __restrict__ lhs_part) {
  const int b    = blockIdx.x / GPB;
  const int gb   = blockIdx.x % GPB;
  const int tid  = threadIdx.x;
  const int wave = tid >> 6;
  const int lane = tid & 63;
  const int frow = lane >> 3;        // 0..7
  const int t4   = (lane & 7) * 4;   // 0,4,...,28

  float u3v[8];
#pragma unroll
  for (int i = 0; i < 8; ++i) u3v[i] = U3[frow + 8 * i];

  float4 lacc[8];
#pragma unroll
  for (int i = 0; i < 8; ++i) lacc[i] = make_float4(0.f, 0.f, 0.f, 0.f);

  const int wb = gb * 4 + wave;  // 0..255
  for (int n = wb; n < NDIM; n += GPB * 4) {
    const float* base = x + ((size_t)(b * NDIM + n)) * (FDIM * TDIM);
    const float u1n = U1[n];
    float4 racc = make_float4(0.f, 0.f, 0.f, 0.f);
#pragma unroll
    for (int i = 0; i < 8; ++i) {
      const float4 v = *(const float4*)(base + (frow + 8 * i) * TDIM + t4);
      lacc[i].x = fmaf(u1n, v.x, lacc[i].x);
      lacc[i].y = fmaf(u1n, v.y, lacc[i].y);
      lacc[i].z = fmaf(u1n, v.z, lacc[i].z);
      lacc[i].w = fmaf(u1n, v.w, lacc[i].w);
      racc.x = fmaf(u3v[i], v.x, racc.x);
      racc.y = fmaf(u3v[i], v.y, racc.y);
      racc.z = fmaf(u3v[i], v.z, racc.z);
      racc.w = fmaf(u3v[i], v.w, racc.w);
    }
#pragma unroll
    for (int m = 8; m <= 32; m <<= 1) {
      racc.x += __shfl_xor(racc.x, m, 64);
      racc.y += __shfl_xor(racc.y, m, 64);
      racc.z += __shfl_xor(racc.z, m, 64);
      racc.w += __shfl_xor(racc.w, m, 64);
    }
    if (frow == 0) {
      *(float4*)(rhs_ws + ((size_t)(b * NDIM + n)) * TDIM + t4) = racc;
    }
  }

  // reduce lhs1 partials across the 4 waves via LDS, write block partial
  __shared__ float sred[4 * 2048];
  float* my = sred + wave * 2048;
#pragma unroll
  for (int i = 0; i < 8; ++i)
    *(float4*)(my + (frow + 8 * i) * TDIM + t4) = lacc[i];
  __syncthreads();
  float* outp = lhs_part + ((size_t)(b * GPB + gb)) * 2048;
  for (int p = tid; p < 2048; p += 256)
    outp[p] = sred[p] + sred[2048 + p] + sred[4096 + p] + sred[6144 + p];
}

// ---------------- kernel 2: fused lhs-reduce + R2 + product/sigmoid/Ve/softmax
// grid = BDIM blocks x 1024 threads. All small tensors; ~5-10us.
__global__ __launch_bounds__(1024) void k2_fused(
    const float* __restrict__ lhs_part, const float* __restrict__ rhs_ws,
    const float* __restrict__ U2, const float* __restrict__ b_e,
    const float* __restrict__ V_e, float* __restrict__ out) {
  const int b = blockIdx.x;
  const int tid = threadIdx.x;
  __shared__ float sl[2048];   // lhs1[f*32+t]
  __shared__ float sR[2048];   // R2[f*32+s]
  __shared__ float sS[1024], sE[1024], sVe[1024], sbe[1024];
  __shared__ float smax[32], ssum[32];

  // Stage A: lhs1 = sum over GPB partials
  for (int p = tid; p < 2048; p += 1024) {
    const float* src = lhs_part + (size_t)b * GPB * 2048 + p;
    float s = 0.f;
#pragma unroll
    for (int g = 0; g < GPB; ++g) s += src[g * 2048];
    sl[p] = s;
  }
  sVe[tid] = V_e[tid];
  sbe[tid] = b_e[tid];

  // Stage B: R2[f,s] = sum_n U2[f,n]*rhs[b,n,s]; thread handles f=f2 and f2+32
  const int f2 = tid >> 5, s = tid & 31;
  const float* rbase = rhs_ws + (size_t)b * NDIM * TDIM;
  const float* u2a = U2 + (size_t)f2 * NDIM;
  const float* u2b = U2 + (size_t)(f2 + 32) * NDIM;
  float a0 = 0.f, a1 = 0.f;
#pragma unroll 8
  for (int n = 0; n < NDIM; ++n) {
    const float v = rbase[n * TDIM + s];
    a0 = fmaf(u2a[n], v, a0);
    a1 = fmaf(u2b[n], v, a1);
  }
  sR[f2 * 32 + s] = a0;
  sR[(f2 + 32) * 32 + s] = a1;
  __syncthreads();

  // Stage C: product (t,s), sigmoid, V_e matmul, softmax over u
  const int t = tid >> 5;  // t == f2 decomposition reused as (t,s)
  float p = 0.f;
#pragma unroll
  for (int f = 0; f < FDIM; ++f) p = fmaf(sl[f * 32 + t], sR[f * 32 + s], p);
  sS[t * 32 + s] = 1.f / (1.f + expf(-(p + sbe[t * 32 + s])));
  __syncthreads();
  float e = 0.f;
#pragma unroll
  for (int tt = 0; tt < 32; ++tt) e = fmaf(sVe[t * 32 + tt], sS[tt * 32 + s], e);
  sE[t * 32 + s] = e;  // t plays the role of u here
  __syncthreads();
  if (tid < 32) {
    float m = -1e30f;
    for (int uu = 0; uu < 32; ++uu) m = fmaxf(m, sE[uu * 32 + tid]);
    float sum = 0.f;
    for (int uu = 0; uu < 32; ++uu) sum += expf(sE[uu * 32 + tid] - m);
    smax[tid] = m;
    ssum[tid] = sum;
  }
  __syncthreads();
  out[b * 1024 + t * 32 + s] = expf(sE[t * 32 + s] - smax[s]) / ssum[s];
}

extern "C" void kernel_launch(void* const* d_in, const int* in_sizes, int n_in,
                              void* d_out, int out_size, void* d_ws, size_t ws_size,
                              hipStream_t stream) {
  const float* x   = (const float*)d_in[0];
  const float* U1  = (const float*)d_in[1];
  const float* U2  = (const float*)d_in[2];
  const float* U3  = (const float*)d_in[3];
  const float* b_e = (const float*)d_in[4];
  const float* V_e = (const float*)d_in[5];
  float* out = (float*)d_out;
  float* ws  = (float*)d_ws;

  // ws layout (floats): rhs 1,048,576 | lhs_part 16*64*2048 = 2,097,152
  float* rhs_ws   = ws;
  float* lhs_part = ws + 1048576;

  k1_pass<<<BDIM * GPB, 256, 0, stream>>>(x, U1, U3, rhs_ws, lhs_part);
  k2_fused<<<BDIM, 1024, 0, stream>>>(lhs_part, rhs_ws, U2, b_e, V_e, out);
}

// Round 3
// 386.730 us; speedup vs baseline: 1.4449x; 1.4449x over previous
//
#include <hip/hip_runtime.h>
#include <math.h>

// B=16, N=2048, F=64, T=32; x:(B,N,F,T) fp32 256MiB; out:(B,T,T) fp32.
// Factorization:
//   lhs1[b,t,f] = sum_n x[b,n,f,t]*U1[n]
//   rhs[b,n,t]  = sum_f U3[f]*x[b,n,f,t]
//   R2[b,f,s]   = sum_n U2[f,n]*rhs[b,n,s]
//   product[b,t,s] = sum_f lhs1[b,t,f]*R2[b,f,s]
//   E = V_e @ sigmoid(product + b_e);  softmax over axis 1 (u).
// k1 is the only HBM-heavy pass (256MB): roofline ~43us. Everything else
// must be wide (>=256 blocks) or tiny; R2's VALU floor is ~3.4us.

#define BDIM 16
#define NDIM 2048
#define FDIM 64
#define TDIM 32
#define GPB  32   // k1 blocks per batch (512 total, 2/CU, 8 waves/CU)
#define NC   16   // R2 n-chunks (256 blocks)

// ---------------- kernel 1: single pass over x ----------------
__global__ __launch_bounds__(256) void k1_pass(
    const float* __restrict__ x, const float* __restrict__ U1,
    const float* __restrict__ U3, float* __restrict__ rhs_ws,
    float* __restrict__ lhs_part) {
  const int b    = blockIdx.x / GPB;
  const int gb   = blockIdx.x % GPB;
  const int tid  = threadIdx.x;
  const int wave = tid >> 6;
  const int lane = tid & 63;
  const int frow = lane >> 3;        // 0..7
  const int t4   = (lane & 7) * 4;   // 0,4,...,28

  float u3v[8];
#pragma unroll
  for (int i = 0; i < 8; ++i) u3v[i] = U3[frow + 8 * i];

  float4 lacc[8];
#pragma unroll
  for (int i = 0; i < 8; ++i) lacc[i] = make_float4(0.f, 0.f, 0.f, 0.f);

  const int wb = gb * 4 + wave;  // 0..127
  for (int n = wb; n < NDIM; n += GPB * 4) {
    const float* base = x + ((size_t)(b * NDIM + n)) * (FDIM * TDIM);
    const float u1n = U1[n];
    float4 racc = make_float4(0.f, 0.f, 0.f, 0.f);
#pragma unroll
    for (int i = 0; i < 8; ++i) {
      const float4 v = *(const float4*)(base + (frow + 8 * i) * TDIM + t4);
      lacc[i].x = fmaf(u1n, v.x, lacc[i].x);
      lacc[i].y = fmaf(u1n, v.y, lacc[i].y);
      lacc[i].z = fmaf(u1n, v.z, lacc[i].z);
      lacc[i].w = fmaf(u1n, v.w, lacc[i].w);
      racc.x = fmaf(u3v[i], v.x, racc.x);
      racc.y = fmaf(u3v[i], v.y, racc.y);
      racc.z = fmaf(u3v[i], v.z, racc.z);
      racc.w = fmaf(u3v[i], v.w, racc.w);
    }
#pragma unroll
    for (int m = 8; m <= 32; m <<= 1) {
      racc.x += __shfl_xor(racc.x, m, 64);
      racc.y += __shfl_xor(racc.y, m, 64);
      racc.z += __shfl_xor(racc.z, m, 64);
      racc.w += __shfl_xor(racc.w, m, 64);
    }
    if (frow == 0) {
      *(float4*)(rhs_ws + ((size_t)(b * NDIM + n)) * TDIM + t4) = racc;
    }
  }

  __shared__ __align__(16) float sred[4 * 2048];
  float* my = sred + wave * 2048;
#pragma unroll
  for (int i = 0; i < 8; ++i)
    *(float4*)(my + (frow + 8 * i) * TDIM + t4) = lacc[i];
  __syncthreads();
  float* outp = lhs_part + ((size_t)(b * GPB + gb)) * 2048;
  for (int p = tid; p < 2048; p += 256)
    outp[p] = sred[p] + sred[2048 + p] + sred[4096 + p] + sred[6144 + p];
}

// ---------------- kernel 2: R2 partials ----------------
// grid = B*NC = 256 blocks (1/CU). Block (b,nc): n-range [nc*128, +128).
// LDS-staged rhs^T (stride 130) and U2 chunk (stride 129) — both 2-way-bank
// safe (free). Thread = (nsub 0..3 | fi 0..15 | si 0..3): 4f x 8s register
// tile over 32 n. FMA floor ~8.2K cyc/CU.
__global__ __launch_bounds__(256) void k2_r2(
    const float* __restrict__ rhs_ws, const float* __restrict__ U2,
    float* __restrict__ R2_part) {
  const int b  = blockIdx.x >> 4;
  const int nc = blockIdx.x & 15;
  const int tid = threadIdx.x;

  __shared__ float srhsT[32 * 130];        // [s][n]
  __shared__ float sU2[64 * 129];          // [f][n]
  __shared__ __align__(16) float sAcc[4 * 2048];

  // stage rhs chunk, transposed
  const float* rbase = rhs_ws + ((size_t)b * NDIM + nc * 128) * TDIM;
  for (int i = tid; i < 1024; i += 256) {  // over float4s of [n][s]
    const float4 v = ((const float4*)rbase)[i];
    const int n  = i >> 3;
    const int s0 = (i & 7) * 4;
    srhsT[(s0 + 0) * 130 + n] = v.x;
    srhsT[(s0 + 1) * 130 + n] = v.y;
    srhsT[(s0 + 2) * 130 + n] = v.z;
    srhsT[(s0 + 3) * 130 + n] = v.w;
  }
  // stage U2 chunk
  const float* ubase = U2 + nc * 128;
  for (int i = tid; i < 2048; i += 256) {  // f = i>>5, c = (i&31)*4
    const int f = i >> 5, c = (i & 31) * 4;
    const float4 u = *(const float4*)(ubase + (size_t)f * NDIM + c);
    sU2[f * 129 + c + 0] = u.x;
    sU2[f * 129 + c + 1] = u.y;
    sU2[f * 129 + c + 2] = u.z;
    sU2[f * 129 + c + 3] = u.w;
  }
  __syncthreads();

  const int lane = tid & 63;
  const int nsub = tid >> 6;
  const int f0 = (lane >> 2) * 4;
  const int s0 = (lane & 3) * 8;
  float acc[4][8];
#pragma unroll
  for (int k = 0; k < 4; ++k)
#pragma unroll
    for (int m = 0; m < 8; ++m) acc[k][m] = 0.f;

  for (int nn = 0; nn < 32; ++nn) {
    const int n = nsub * 32 + nn;
    float u[4], v[8];
#pragma unroll
    for (int k = 0; k < 4; ++k) u[k] = sU2[(f0 + k) * 129 + n];
#pragma unroll
    for (int m = 0; m < 8; ++m) v[m] = srhsT[(s0 + m) * 130 + n];
#pragma unroll
    for (int k = 0; k < 4; ++k)
#pragma unroll
      for (int m = 0; m < 8; ++m) acc[k][m] = fmaf(u[k], v[m], acc[k][m]);
  }
#pragma unroll
  for (int k = 0; k < 4; ++k)
#pragma unroll
    for (int m = 0; m < 8; ++m)
      sAcc[nsub * 2048 + (f0 + k) * 32 + s0 + m] = acc[k][m];
  __syncthreads();

  float4* dst = (float4*)(R2_part + ((size_t)(b * NC + nc)) * 2048);
  const float4* sa = (const float4*)sAcc;
  for (int i = tid; i < 512; i += 256) {
    float4 r0 = sa[i], r1 = sa[512 + i], r2 = sa[1024 + i], r3 = sa[1536 + i];
    r0.x += r1.x + r2.x + r3.x;
    r0.y += r1.y + r2.y + r3.y;
    r0.z += r1.z + r2.z + r3.z;
    r0.w += r1.w + r2.w + r3.w;
    dst[i] = r0;
  }
}

// ---------------- kernel 3: partial-reduces + epilogue ----------------
__global__ __launch_bounds__(1024) void k3(
    const float* __restrict__ lhs_part, const float* __restrict__ R2_part,
    const float* __restrict__ b_e, const float* __restrict__ V_e,
    float* __restrict__ out) {
  const int b = blockIdx.x;
  const int tid = threadIdx.x;
  __shared__ __align__(16) float sl2[4096], sRp[4096];
  __shared__ float sl[2048], sR[2048];
  __shared__ float sS[1024], sE[1024], sVe[1024], sbe[1024];
  __shared__ float smax[32], ssum[32];

  const int half = tid >> 9;
  const int p4 = (tid & 511) * 4;

  // lhs1 partial-reduce: g over [half*16, +16), coalesced float4
  {
    const float* lpb = lhs_part + (size_t)b * GPB * 2048;
    float4 a = make_float4(0.f, 0.f, 0.f, 0.f);
#pragma unroll
    for (int g = 0; g < 16; ++g) {
      const float4 v = *(const float4*)(lpb + (half * 16 + g) * 2048 + p4);
      a.x += v.x; a.y += v.y; a.z += v.z; a.w += v.w;
    }
    *(float4*)(sl2 + half * 2048 + p4) = a;
  }
  // R2 partial-reduce: nc over [half*8, +8)
  {
    const float* rpb = R2_part + (size_t)b * NC * 2048;
    float4 a = make_float4(0.f, 0.f, 0.f, 0.f);
#pragma unroll
    for (int nc = 0; nc < 8; ++nc) {
      const float4 v = *(const float4*)(rpb + (half * 8 + nc) * 2048 + p4);
      a.x += v.x; a.y += v.y; a.z += v.z; a.w += v.w;
    }
    *(float4*)(sRp + half * 2048 + p4) = a;
  }
  sVe[tid] = V_e[tid];
  sbe[tid] = b_e[tid];
  __syncthreads();
  {
    int p = tid;
    sl[p] = sl2[p] + sl2[2048 + p];
    sR[p] = sRp[p] + sRp[2048 + p];
    p = tid + 1024;
    sl[p] = sl2[p] + sl2[2048 + p];
    sR[p] = sRp[p] + sRp[2048 + p];
  }
  __syncthreads();

  // product (t,s), sigmoid, V_e matmul, softmax over u (verified epilogue)
  const int t = tid >> 5, s = tid & 31;
  float p = 0.f;
#pragma unroll
  for (int f = 0; f < FDIM; ++f) p = fmaf(sl[f * 32 + t], sR[f * 32 + s], p);
  sS[t * 32 + s] = 1.f / (1.f + expf(-(p + sbe[t * 32 + s])));
  __syncthreads();
  float e = 0.f;
#pragma unroll
  for (int tt = 0; tt < 32; ++tt) e = fmaf(sVe[t * 32 + tt], sS[tt * 32 + s], e);
  sE[t * 32 + s] = e;
  __syncthreads();
  if (tid < 32) {
    float m = -1e30f;
    for (int uu = 0; uu < 32; ++uu) m = fmaxf(m, sE[uu * 32 + tid]);
    float sum = 0.f;
    for (int uu = 0; uu < 32; ++uu) sum += expf(sE[uu * 32 + tid] - m);
    smax[tid] = m;
    ssum[tid] = sum;
  }
  __syncthreads();
  out[b * 1024 + t * 32 + s] = expf(sE[t * 32 + s] - smax[s]) / ssum[s];
}

extern "C" void kernel_launch(void* const* d_in, const int* in_sizes, int n_in,
                              void* d_out, int out_size, void* d_ws, size_t ws_size,
                              hipStream_t stream) {
  const float* x   = (const float*)d_in[0];
  const float* U1  = (const float*)d_in[1];
  const float* U2  = (const float*)d_in[2];
  const float* U3  = (const float*)d_in[3];
  const float* b_e = (const float*)d_in[4];
  const float* V_e = (const float*)d_in[5];
  float* out = (float*)d_out;
  float* ws  = (float*)d_ws;

  // ws layout (floats): rhs 1,048,576 | lhs_part GPB*2048*16 = 1,048,576 |
  //                     R2_part B*NC*2048 = 524,288   (total ~10.5 MB)
  float* rhs_ws   = ws;
  float* lhs_part = ws + 1048576;
  float* R2_part  = ws + 2097152;

  k1_pass<<<BDIM * GPB, 256, 0, stream>>>(x, U1, U3, rhs_ws, lhs_part);
  k2_r2<<<BDIM * NC, 256, 0, stream>>>(rhs_ws, U2, R2_part);
  k3<<<BDIM, 1024, 0, stream>>>(lhs_part, R2_part, b_e, V_e, out);
}

// Round 4
// 386.144 us; speedup vs baseline: 1.4471x; 1.0015x over previous
//
#include <hip/hip_runtime.h>
#include <math.h>

// B=16, N=2048, F=64, T=32; x:(B,N,F,T) fp32 256MiB; out:(B,T,T) fp32.
// Factorization:
//   lhs1[b,t,f] = sum_n x[b,n,f,t]*U1[n]
//   rhs[b,n,t]  = sum_f U3[f]*x[b,n,f,t]
//   R2[b,f,s]   = sum_n U2[f,n]*rhs[b,n,s]
//   product[b,t,s] = sum_f lhs1[b,t,f]*R2[b,f,s]
//   E = V_e @ sigmoid(product + b_e);  softmax over axis 1 (u).
// k1 (268MB x-read) is the only HBM-heavy pass: floor ~43us. Harness adds
// ~320us of ws-poison fills per iteration (measured, fillBufferAligned).

#define BDIM 16
#define NDIM 2048
#define FDIM 64
#define TDIM 32
#define GPB  32   // k1 blocks per batch (512 total, 2/CU, 8 waves/CU)
#define NC   16   // R2 n-chunks (256 blocks)

// ---------------- kernel 1: single pass over x (unchanged, ~45us) ----------
__global__ __launch_bounds__(256) void k1_pass(
    const float* __restrict__ x, const float* __restrict__ U1,
    const float* __restrict__ U3, float* __restrict__ rhs_ws,
    float* __restrict__ lhs_part) {
  const int b    = blockIdx.x / GPB;
  const int gb   = blockIdx.x % GPB;
  const int tid  = threadIdx.x;
  const int wave = tid >> 6;
  const int lane = tid & 63;
  const int frow = lane >> 3;        // 0..7
  const int t4   = (lane & 7) * 4;   // 0,4,...,28

  float u3v[8];
#pragma unroll
  for (int i = 0; i < 8; ++i) u3v[i] = U3[frow + 8 * i];

  float4 lacc[8];
#pragma unroll
  for (int i = 0; i < 8; ++i) lacc[i] = make_float4(0.f, 0.f, 0.f, 0.f);

  const int wb = gb * 4 + wave;  // 0..127
  for (int n = wb; n < NDIM; n += GPB * 4) {
    const float* base = x + ((size_t)(b * NDIM + n)) * (FDIM * TDIM);
    const float u1n = U1[n];
    float4 racc = make_float4(0.f, 0.f, 0.f, 0.f);
#pragma unroll
    for (int i = 0; i < 8; ++i) {
      const float4 v = *(const float4*)(base + (frow + 8 * i) * TDIM + t4);
      lacc[i].x = fmaf(u1n, v.x, lacc[i].x);
      lacc[i].y = fmaf(u1n, v.y, lacc[i].y);
      lacc[i].z = fmaf(u1n, v.z, lacc[i].z);
      lacc[i].w = fmaf(u1n, v.w, lacc[i].w);
      racc.x = fmaf(u3v[i], v.x, racc.x);
      racc.y = fmaf(u3v[i], v.y, racc.y);
      racc.z = fmaf(u3v[i], v.z, racc.z);
      racc.w = fmaf(u3v[i], v.w, racc.w);
    }
#pragma unroll
    for (int m = 8; m <= 32; m <<= 1) {
      racc.x += __shfl_xor(racc.x, m, 64);
      racc.y += __shfl_xor(racc.y, m, 64);
      racc.z += __shfl_xor(racc.z, m, 64);
      racc.w += __shfl_xor(racc.w, m, 64);
    }
    if (frow == 0) {
      *(float4*)(rhs_ws + ((size_t)(b * NDIM + n)) * TDIM + t4) = racc;
    }
  }

  __shared__ __align__(16) float sred[4 * 2048];
  float* my = sred + wave * 2048;
#pragma unroll
  for (int i = 0; i < 8; ++i)
    *(float4*)(my + (frow + 8 * i) * TDIM + t4) = lacc[i];
  __syncthreads();
  float* outp = lhs_part + ((size_t)(b * GPB + gb)) * 2048;
  for (int p = tid; p < 2048; p += 256)
    outp[p] = sred[p] + sred[2048 + p] + sred[4096 + p] + sred[6144 + p];
}

// ---------------- kernel 2: R2 partials + folded lhs1 reduce ----------------
// grid = B*NC = 256 blocks (1/CU). Block (b,nc): n-range [nc*128, +128) for
// the R2 GEMM partial, plus reduces lhs_part over g for p-slice [nc*128,+128).
__global__ __launch_bounds__(256) void k2_r2(
    const float* __restrict__ rhs_ws, const float* __restrict__ U2,
    const float* __restrict__ lhs_part, float* __restrict__ R2_part,
    float* __restrict__ lhs1) {
  const int b  = blockIdx.x >> 4;
  const int nc = blockIdx.x & 15;
  const int tid = threadIdx.x;

  __shared__ float srhsT[32 * 130];        // [s][n]
  __shared__ float sU2[64 * 129];          // [f][n]
  __shared__ __align__(16) float sAcc[4 * 2048];

  // stage rhs chunk, transposed
  const float* rbase = rhs_ws + ((size_t)b * NDIM + nc * 128) * TDIM;
  for (int i = tid; i < 1024; i += 256) {  // over float4s of [n][s]
    const float4 v = ((const float4*)rbase)[i];
    const int n  = i >> 3;
    const int s0 = (i & 7) * 4;
    srhsT[(s0 + 0) * 130 + n] = v.x;
    srhsT[(s0 + 1) * 130 + n] = v.y;
    srhsT[(s0 + 2) * 130 + n] = v.z;
    srhsT[(s0 + 3) * 130 + n] = v.w;
  }
  // stage U2 chunk
  const float* ubase = U2 + nc * 128;
  for (int i = tid; i < 2048; i += 256) {  // f = i>>5, c = (i&31)*4
    const int f = i >> 5, c = (i & 31) * 4;
    const float4 u = *(const float4*)(ubase + (size_t)f * NDIM + c);
    sU2[f * 129 + c + 0] = u.x;
    sU2[f * 129 + c + 1] = u.y;
    sU2[f * 129 + c + 2] = u.z;
    sU2[f * 129 + c + 3] = u.w;
  }

  // folded lhs1 reduce (independent of LDS; 128 threads, coalesced per g)
  if (tid < 128) {
    const float* lpb = lhs_part + (size_t)b * GPB * 2048 + nc * 128 + tid;
    float s = 0.f;
#pragma unroll
    for (int g = 0; g < GPB; ++g) s += lpb[g * 2048];
    lhs1[b * 2048 + nc * 128 + tid] = s;
  }
  __syncthreads();

  const int lane = tid & 63;
  const int nsub = tid >> 6;
  const int f0 = (lane >> 2) * 4;
  const int s0 = (lane & 3) * 8;
  float acc[4][8];
#pragma unroll
  for (int k = 0; k < 4; ++k)
#pragma unroll
    for (int m = 0; m < 8; ++m) acc[k][m] = 0.f;

  for (int nn = 0; nn < 32; ++nn) {
    const int n = nsub * 32 + nn;
    float u[4], v[8];
#pragma unroll
    for (int k = 0; k < 4; ++k) u[k] = sU2[(f0 + k) * 129 + n];
#pragma unroll
    for (int m = 0; m < 8; ++m) v[m] = srhsT[(s0 + m) * 130 + n];
#pragma unroll
    for (int k = 0; k < 4; ++k)
#pragma unroll
      for (int m = 0; m < 8; ++m) acc[k][m] = fmaf(u[k], v[m], acc[k][m]);
  }
#pragma unroll
  for (int k = 0; k < 4; ++k)
#pragma unroll
    for (int m = 0; m < 8; ++m)
      sAcc[nsub * 2048 + (f0 + k) * 32 + s0 + m] = acc[k][m];
  __syncthreads();

  float4* dst = (float4*)(R2_part + ((size_t)(b * NC + nc)) * 2048);
  const float4* sa = (const float4*)sAcc;
  for (int i = tid; i < 512; i += 256) {
    float4 r0 = sa[i], r1 = sa[512 + i], r2 = sa[1024 + i], r3 = sa[1536 + i];
    r0.x += r1.x + r2.x + r3.x;
    r0.y += r1.y + r2.y + r3.y;
    r0.z += r1.z + r2.z + r3.z;
    r0.w += r1.w + r2.w + r3.w;
    dst[i] = r0;
  }
}

// ---------------- kernel 3: small reduce + epilogue (reads ~136KB/block) ----
__global__ __launch_bounds__(1024) void k3(
    const float* __restrict__ lhs1, const float* __restrict__ R2_part,
    const float* __restrict__ b_e, const float* __restrict__ V_e,
    float* __restrict__ out) {
  const int b = blockIdx.x;
  const int tid = threadIdx.x;
  __shared__ float sl[2048], sR[2048];
  __shared__ float sS[1024], sE[1024], sVe[1024], sbe[1024];
  __shared__ float smax[32], ssum[32];

  for (int p = tid; p < 2048; p += 1024) sl[p] = lhs1[b * 2048 + p];
  if (tid < 512) {
    const float* rpb = R2_part + (size_t)b * NC * 2048;
    float4 a = make_float4(0.f, 0.f, 0.f, 0.f);
#pragma unroll
    for (int nc = 0; nc < NC; ++nc) {
      const float4 v = *(const float4*)(rpb + nc * 2048 + tid * 4);
      a.x += v.x; a.y += v.y; a.z += v.z; a.w += v.w;
    }
    *(float4*)(sR + tid * 4) = a;
  }
  sVe[tid] = V_e[tid];
  sbe[tid] = b_e[tid];
  __syncthreads();

  // product (t,s), sigmoid, V_e matmul, softmax over u (verified epilogue)
  const int t = tid >> 5, s = tid & 31;
  float p = 0.f;
#pragma unroll
  for (int f = 0; f < FDIM; ++f) p = fmaf(sl[f * 32 + t], sR[f * 32 + s], p);
  sS[t * 32 + s] = 1.f / (1.f + expf(-(p + sbe[t * 32 + s])));
  __syncthreads();
  float e = 0.f;
#pragma unroll
  for (int tt = 0; tt < 32; ++tt) e = fmaf(sVe[t * 32 + tt], sS[tt * 32 + s], e);
  sE[t * 32 + s] = e;
  __syncthreads();
  if (tid < 32) {
    float m = -1e30f;
    for (int uu = 0; uu < 32; ++uu) m = fmaxf(m, sE[uu * 32 + tid]);
    float sum = 0.f;
    for (int uu = 0; uu < 32; ++uu) sum += expf(sE[uu * 32 + tid] - m);
    smax[tid] = m;
    ssum[tid] = sum;
  }
  __syncthreads();
  out[b * 1024 + t * 32 + s] = expf(sE[t * 32 + s] - smax[s]) / ssum[s];
}

extern "C" void kernel_launch(void* const* d_in, const int* in_sizes, int n_in,
                              void* d_out, int out_size, void* d_ws, size_t ws_size,
                              hipStream_t stream) {
  const float* x   = (const float*)d_in[0];
  const float* U1  = (const float*)d_in[1];
  const float* U2  = (const float*)d_in[2];
  const float* U3  = (const float*)d_in[3];
  const float* b_e = (const float*)d_in[4];
  const float* V_e = (const float*)d_in[5];
  float* out = (float*)d_out;
  float* ws  = (float*)d_ws;

  // ws layout (floats): rhs 1,048,576 | lhs_part 1,048,576 |
  //                     R2_part 524,288 | lhs1 32,768   (~10.6 MB)
  float* rhs_ws   = ws;
  float* lhs_part = ws + 1048576;
  float* R2_part  = ws + 2097152;
  float* lhs1     = ws + 2097152 + 524288;

  k1_pass<<<BDIM * GPB, 256, 0, stream>>>(x, U1, U3, rhs_ws, lhs_part);
  k2_r2<<<BDIM * NC, 256, 0, stream>>>(rhs_ws, U2, lhs_part, R2_part, lhs1);
  k3<<<BDIM, 1024, 0, stream>>>(lhs1, R2_part, b_e, V_e, out);
}